// Round 1
// 1149.765 us; speedup vs baseline: 1.1739x; 1.1739x over previous
//
#include <hip/hip_runtime.h>

typedef _Float16 v8h __attribute__((ext_vector_type(8)));
typedef _Float16 v4h __attribute__((ext_vector_type(4)));
typedef float    v4f __attribute__((ext_vector_type(4)));

#define GK 6432      // true K / N of the big GEMM
#define GN 6432
#define GM 2048
#define KP 6528      // K padded to 102*64 for BK=64 8-phase pipeline

// ---------------------------------------------------------------------------
// Weight conversion: wl fp32 [6432,6432] -> fp16 [6432, KP], K-pad cols zeroed
// (rows are NOT padded: the GEMM clamps B source rows to 6431; those values
//  only feed output columns >= 6432 which the epilogue discards/zeroes)
// ---------------------------------------------------------------------------
__global__ void convert_w(const float* __restrict__ wl, _Float16* __restrict__ Wh)
{
    const int row = blockIdx.y;                       // 0..6431
    const int col = (blockIdx.x * 256 + threadIdx.x) * 4;
    if (col >= KP) return;
    v4h h;
    if (col < GK) {                                   // 6432 % 4 == 0: no straddle
        const float4 f = *(const float4*)(wl + (long)row * GK + col);
        h[0] = (_Float16)f.x; h[1] = (_Float16)f.y;
        h[2] = (_Float16)f.z; h[3] = (_Float16)f.w;
    } else {
        h[0] = (_Float16)0.f; h[1] = (_Float16)0.f;
        h[2] = (_Float16)0.f; h[3] = (_Float16)0.f;
    }
    *(v4h*)(Wh + (long)row * KP + col) = h;
}

// ---------------------------------------------------------------------------
// Multi-scale conv feature extractor. One block per batch item.
// Produces F0 [2048, KP] fp16, layout b*KP + c2*201 + v; K-pad cols zeroed.
// ---------------------------------------------------------------------------
#define SX   0
#define SX2  2048
#define SX4  3136
#define SW1  3712
#define SB1  4032
#define SW2  4048
#define SB2  6608
#define SP1  6640
#define LDSZ 13808

__global__ __launch_bounds__(256) void conv_feat(
    const float* __restrict__ x,
    const float* __restrict__ w1, const float* __restrict__ b1,
    const float* __restrict__ w2, const float* __restrict__ b2,
    _Float16* __restrict__ F0)
{
    __shared__ float lds[LDSZ];
    const int tid = threadIdx.x;
    const long b  = blockIdx.x;

    for (int i = tid; i < 1920; i += 256) {
        int c = i / 480, t = i % 480;
        lds[SX + c * 512 + t] = x[(b * 4 + c) * 480 + t];
    }
    for (int i = tid; i < 320;  i += 256) lds[SW1 + i] = w1[i];
    for (int i = tid; i < 16;   i += 256) lds[SB1 + i] = b1[i];
    for (int i = tid; i < 2560; i += 256) lds[SW2 + i] = w2[i];
    for (int i = tid; i < 32;   i += 256) lds[SB2 + i] = b2[i];
    // zero the K-pad columns of this row of F0 (keeps GEMM K-pad products 0)
    for (int i = tid; i < KP - GK; i += 256) F0[b * KP + GK + i] = (_Float16)0.f;
    __syncthreads();

    for (int i = tid; i < 960; i += 256) {
        int c = i / 240, t = i % 240;
        lds[SX2 + c * 272 + t] = 0.5f * (lds[SX + c * 512 + 2 * t] + lds[SX + c * 512 + 2 * t + 1]);
    }
    for (int i = tid; i < 480; i += 256) {
        int c = i / 120, t = i % 120;
        float s = lds[SX + c * 512 + 4 * t]     + lds[SX + c * 512 + 4 * t + 1]
                + lds[SX + c * 512 + 4 * t + 2] + lds[SX + c * 512 + 4 * t + 3];
        lds[SX4 + c * 144 + t] = 0.25f * s;
    }
    __syncthreads();

    for (int jid = tid; jid < 16 * 34; jid += 256) {
        const int c1 = jid / 34, rid = jid % 34;
        const int sidx = (rid < 19) ? 0 : (rid < 29 ? 1 : 2);
        const int r0   = (sidx == 0) ? rid : (sidx == 1 ? rid - 19 : rid - 29);
        const int u0   = r0 * 13;
        const int xbase  = (sidx == 0) ? SX  : (sidx == 1 ? SX2 : SX4);
        const int xpitch = (sidx == 0) ? 512 : (sidx == 1 ? 272 : 144);
        const int P      = (sidx == 0) ? 238 : (sidx == 1 ? 118 : 58);
        const int pofs   = (sidx == 0) ? 0   : (sidx == 1 ? 238 : 356);

        float acc[26];
        const float bias = lds[SB1 + c1];
        #pragma unroll
        for (int i = 0; i < 26; ++i) acc[i] = bias;

        #pragma unroll
        for (int ci = 0; ci < 4; ++ci) {
            float w[30];
            const float* xr = &lds[xbase + ci * xpitch + 2 * u0];
            #pragma unroll
            for (int q = 0; q < 15; ++q) {
                float2 t2 = *(const float2*)(xr + 2 * q);
                w[2 * q] = t2.x; w[2 * q + 1] = t2.y;
            }
            float wt[5];
            #pragma unroll
            for (int k = 0; k < 5; ++k) wt[k] = lds[SW1 + (c1 * 4 + ci) * 5 + k];
            #pragma unroll
            for (int i = 0; i < 26; ++i) {
                #pragma unroll
                for (int k = 0; k < 5; ++k) acc[i] += w[i + k] * wt[k];
            }
        }
        #pragma unroll
        for (int i = 0; i < 13; ++i) {
            int u = u0 + i;
            if (u < P)
                lds[SP1 + c1 * 448 + pofs + u] = fmaxf(fmaxf(acc[2 * i], acc[2 * i + 1]), 0.f);
        }
    }
    __syncthreads();

    for (int jid = tid; jid < 32 * 17; jid += 256) {
        const int c2 = jid / 17, rid = jid % 17;
        const int sidx = (rid < 9) ? 0 : (rid < 14 ? 1 : 2);
        const int r0   = (sidx == 0) ? rid : (sidx == 1 ? rid - 9 : rid - 14);
        const int v0   = r0 * 13;
        const int pbase = (sidx == 0) ? 0   : (sidx == 1 ? 238 : 356);
        const int Pv    = (sidx == 0) ? 117 : (sidx == 1 ? 57  : 27);
        const int vout  = (sidx == 0) ? 0   : (sidx == 1 ? 117 : 174);

        float acc[26];
        const float bias = lds[SB2 + c2];
        #pragma unroll
        for (int i = 0; i < 26; ++i) acc[i] = bias;

        for (int c1 = 0; c1 < 16; ++c1) {
            float w[30];
            const float* pr = &lds[SP1 + c1 * 448 + pbase + 2 * v0];
            #pragma unroll
            for (int q = 0; q < 15; ++q) {
                float2 t2 = *(const float2*)(pr + 2 * q);
                w[2 * q] = t2.x; w[2 * q + 1] = t2.y;
            }
            float wt[5];
            #pragma unroll
            for (int k = 0; k < 5; ++k) wt[k] = lds[SW2 + (c2 * 16 + c1) * 5 + k];
            #pragma unroll
            for (int i = 0; i < 26; ++i) {
                #pragma unroll
                for (int k = 0; k < 5; ++k) acc[i] += w[i + k] * wt[k];
            }
        }
        #pragma unroll
        for (int i = 0; i < 13; ++i) {
            int v = v0 + i;
            if (v < Pv) {
                float f = fmaxf(fmaxf(acc[2 * i], acc[2 * i + 1]), 0.f);
                F0[b * KP + c2 * 201 + vout + v] = (_Float16)f;
            }
        }
    }
}

// ---------------------------------------------------------------------------
// 256x256x(BK=64) 8-phase NT GEMM: C = relu(A @ Bw^T + bias), fp16 in/out,
// fp32 accum. 512 threads = 8 waves (2M x 4N), per-wave 128x64 output.
// T2: XOR-swizzled LDS (phys slot = logical ^ (row&7)), applied via
//     pre-swizzled per-lane GLOBAL source (linear global_load_lds dest)
//     + swizzled ds_read offsets (both-sides-or-neither, m173/m201).
// T3+T4: 4 phases per K-tile, one half-region prefetch per phase,
//     counted s_waitcnt vmcnt(6) once per K-tile (never 0 in main loop).
// T5: s_setprio(1) around each 16-MFMA cluster.
//
// Region-safety of the staging schedule (phase X stages into regions whose
// last ds_read completed before phase X's issue point, enforced by the
// phase-end barriers, since every wave passes lgkmcnt(0) before them):
//   P1 stages B rows 128-255 of OTHER buf (last read: prev round P1/P2)
//   P2 stages A rows {0-63,128-191} of cur buf (read at P1 only)
//   P3 stages B rows 0-127       of cur buf (read at P1+P2)
//   P4 stages A rows {64-127,192-255} of cur buf (read at P3 only)
// vmcnt(6) at P4 end: the 6 newest outstanding loads are this round's
// P2/P3/P4 stages; everything older - i.e. ALL of next tile's staging,
// whose last chunk went out at P1 of this round - has landed. Barrier
// after it makes that guarantee cross-wave before next round's ds_reads.
// ---------------------------------------------------------------------------
__global__ __launch_bounds__(512, 2) void gemm8(
    const _Float16* __restrict__ A, const _Float16* __restrict__ Bw,
    const float* __restrict__ bias, _Float16* __restrict__ C)
{
    __shared__ _Float16 sA[2][256 * 64];   // 32 KB per buf
    __shared__ _Float16 sB[2][256 * 64];   // total LDS = 128 KB

    const int tid  = threadIdx.x;
    const int lane = tid & 63;
    const int wave = tid >> 6;           // 0..7
    const int wr   = wave >> 2;          // m-half of tile (0..1)
    const int wc   = wave & 3;           // n-quarter of tile (0..3)

    // grid 208 = 8 m-tiles x 26 n-tiles. m-tile = XCD id (id&7): each XCD's
    // 256-row A strip (3.3 MB) stays L2-resident across its 26 n-tiles.
    const int id  = blockIdx.x;
    const long tile_m = (long)(id & 7) << 8;
    const long tile_n = (long)(id >> 3) << 8;

    // ---- staging geometry: 1 inst = 8 rows x 64 k (1 KB), linear LDS dest.
    // lane l writes LDS (row0+(l>>3), slot l&7); source k-slot pre-XORed so
    // physical slot = logical ^ (row&7).
    const int lrow = lane >> 3;                  // 0..7
    const int lcol = ((lane & 7) ^ lrow) << 3;   // fp16 elems
    const int rA1  = wave * 16 + ((wave & 4) << 4);  // rows in {0-63,128-191}
    const int rA2  = rA1 + 64;                       // rows in {64-127,192-255}
    const int rB1  = wave * 16;                      // rows 0-127
    const int rB2  = rB1 + 128;                      // rows 128-255

    const _Float16* gA = A  + (tile_m + lrow) * (long)KP + lcol;
    const _Float16* gB = Bw + lcol;

#define STAGE_A(buf, row0, k0)                                                             \
    {                                                                                      \
        __builtin_amdgcn_global_load_lds(                                                  \
            (const __attribute__((address_space(1))) void*)(gA + (long)(row0) * KP + (k0)),\
            (__attribute__((address_space(3))) void*)(&sA[buf][(row0) * 64]), 16, 0, 0);   \
        __builtin_amdgcn_global_load_lds(                                                  \
            (const __attribute__((address_space(1))) void*)(gA + (long)((row0) + 8) * KP + (k0)), \
            (__attribute__((address_space(3))) void*)(&sA[buf][((row0) + 8) * 64]), 16, 0, 0);    \
    }

// B rows >= 6432 (last n-tile only) are clamped to row 6431: finite garbage
// that feeds only the discarded output columns.
#define STAGE_B(buf, row0, k0)                                                             \
    {                                                                                      \
        long r0_ = tile_n + (row0) + lrow;     if (r0_ > 6431) r0_ = 6431;                 \
        long r1_ = r0_ + 8;                    if (r1_ > 6431) r1_ = 6431;                 \
        __builtin_amdgcn_global_load_lds(                                                  \
            (const __attribute__((address_space(1))) void*)(gB + r0_ * KP + (k0)),         \
            (__attribute__((address_space(3))) void*)(&sB[buf][(row0) * 64]), 16, 0, 0);   \
        __builtin_amdgcn_global_load_lds(                                                  \
            (const __attribute__((address_space(1))) void*)(gB + r1_ * KP + (k0)),         \
            (__attribute__((address_space(3))) void*)(&sB[buf][((row0) + 8) * 64]), 16, 0, 0);    \
    }

    // ---- fragment read offsets (swizzled ds_read_b128) ----
    const int fr = lane & 15;
    const int fp = lane >> 4;                    // k-phase 0..3
    const int sw = fr & 7;                       // row&7 (frag row bases are x16)
    const int slot0 = (fp ^ sw) << 3;            // ks=0: logical slot fp
    const int slot1 = ((fp + 4) ^ sw) << 3;      // ks=1: logical slot 4+fp
    const int abase = (wr * 128 + fr) * 64;
    const int bbase = (wc * 64 + fr) * 64;

    v8h af[4][2], bf0[2][2], bf1[2][2];
    v4f acc[8][4];
    #pragma unroll
    for (int i = 0; i < 8; ++i) {
        #pragma unroll
        for (int j = 0; j < 4; ++j) { v4f z = {0.f, 0.f, 0.f, 0.f}; acc[i][j] = z; }
    }

#define LDA(base, h)                                                                       \
    { _Pragma("unroll")                                                                    \
      for (int mi = 0; mi < 4; ++mi) {                                                     \
          af[mi][0] = *(const v8h*)((base) + abase + (h) * 4096 + mi * 1024 + slot0);      \
          af[mi][1] = *(const v8h*)((base) + abase + (h) * 4096 + mi * 1024 + slot1);      \
      } }

#define LDB(base, h, bf)                                                                   \
    { _Pragma("unroll")                                                                    \
      for (int ni = 0; ni < 2; ++ni) {                                                     \
          bf[ni][0] = *(const v8h*)((base) + bbase + (h) * 2048 + ni * 1024 + slot0);      \
          bf[ni][1] = *(const v8h*)((base) + bbase + (h) * 2048 + ni * 1024 + slot1);      \
      } }

#define MMAQ(mh, nh, bf)                                                                   \
    { _Pragma("unroll")                                                                    \
      for (int mi = 0; mi < 4; ++mi) {                                                     \
          _Pragma("unroll")                                                                \
          for (int ni = 0; ni < 2; ++ni) {                                                 \
              acc[(mh)*4+mi][(nh)*2+ni] = __builtin_amdgcn_mfma_f32_16x16x32_f16(          \
                  af[mi][0], bf[ni][0], acc[(mh)*4+mi][(nh)*2+ni], 0, 0, 0);               \
              acc[(mh)*4+mi][(nh)*2+ni] = __builtin_amdgcn_mfma_f32_16x16x32_f16(          \
                  af[mi][1], bf[ni][1], acc[(mh)*4+mi][(nh)*2+ni], 0, 0, 0);               \
          } } }

    // ---- prologue: tile0 full + tile1 {A1,B1,A2} (its B2 comes at P1 of kt=0)
    STAGE_A(0, rA1, 0);  STAGE_B(0, rB1, 0);  STAGE_A(0, rA2, 0);  STAGE_B(0, rB2, 0);
    STAGE_A(1, rA1, 64); STAGE_B(1, rB1, 64); STAGE_A(1, rA2, 64);
    asm volatile("s_waitcnt vmcnt(6)" ::: "memory");   // tile0's 8 landed
    __builtin_amdgcn_s_barrier();

    int b = 0;
    #pragma unroll 2
    for (int kt = 0; kt < 102; ++kt, b ^= 1) {
        const _Float16* cA = sA[b];
        const _Float16* cB = sB[b];
        const int k1 = (kt + 1) << 6;
        const int k2 = (kt + 2) << 6;
        const bool s1 = kt < 101;      // stage tile kt+1's B2
        const bool s2 = kt < 100;      // stage tile kt+2

        // P1: read A-mh0 + B-nh0; prefetch next tile's B rows 128-255
        LDA(cA, 0); LDB(cB, 0, bf0);
        if (s1) STAGE_B(b ^ 1, rB2, k1);
        __builtin_amdgcn_s_barrier();
        asm volatile("s_waitcnt lgkmcnt(0)" ::: "memory");
        __builtin_amdgcn_s_setprio(1);
        MMAQ(0, 0, bf0);
        __builtin_amdgcn_s_setprio(0);
        __builtin_amdgcn_s_barrier();

        // P2: read B-nh1; prefetch tile kt+2's A rows {0-63,128-191}
        LDB(cB, 1, bf1);
        if (s2) STAGE_A(b, rA1, k2);
        __builtin_amdgcn_s_barrier();
        asm volatile("s_waitcnt lgkmcnt(0)" ::: "memory");
        __builtin_amdgcn_s_setprio(1);
        MMAQ(0, 1, bf1);
        __builtin_amdgcn_s_setprio(0);
        __builtin_amdgcn_s_barrier();

        // P3: read A-mh1; prefetch tile kt+2's B rows 0-127
        LDA(cA, 1);
        if (s2) STAGE_B(b, rB1, k2);
        __builtin_amdgcn_s_barrier();
        asm volatile("s_waitcnt lgkmcnt(0)" ::: "memory");
        __builtin_amdgcn_s_setprio(1);
        MMAQ(1, 1, bf1);
        __builtin_amdgcn_s_setprio(0);
        __builtin_amdgcn_s_barrier();

        // P4: prefetch tile kt+2's A rows {64-127,192-255}; counted vmcnt
        if (s2) STAGE_A(b, rA2, k2);
        __builtin_amdgcn_s_barrier();
        __builtin_amdgcn_s_setprio(1);
        MMAQ(1, 0, bf0);
        __builtin_amdgcn_s_setprio(0);
        if (s2) { asm volatile("s_waitcnt vmcnt(6)" ::: "memory"); }
        else    { asm volatile("s_waitcnt vmcnt(0)" ::: "memory"); }
        __builtin_amdgcn_s_barrier();
    }

    // ---- epilogue: C/D layout col=lane&15, row=(lane>>4)*4+reg (m89-verified)
    const long ccol0 = tile_n + wc * 64 + fr;
    #pragma unroll
    for (int n = 0; n < 4; ++n) {
        const long col = ccol0 + n * 16;
        if (col < KP) {
            const bool valid = col < GN;
            const float bv = valid ? bias[col] : 0.f;
            #pragma unroll
            for (int m = 0; m < 8; ++m) {
                const long row = tile_m + wr * 128 + m * 16 + fp * 4;
                #pragma unroll
                for (int r = 0; r < 4; ++r) {
                    float v = acc[m][n][r] + bv;
                    v = v > 0.f ? v : 0.f;
                    // pad cols [6432,6528) get 0: they are the K-pad of the
                    // next GEMM's A operand
                    C[(row + r) * (long)KP + col] = valid ? (_Float16)v : (_Float16)0.f;
                }
            }
        }
    }
#undef STAGE_A
#undef STAGE_B
#undef LDA
#undef LDB
#undef MMAQ
}

// ---------------------------------------------------------------------------
// Final projection: out[b,o] = sum_k F[b,k]*wo[o,k] + bo[o].
// ---------------------------------------------------------------------------
__global__ __launch_bounds__(256) void final_out(
    const _Float16* __restrict__ F, const float* __restrict__ wo,
    const float* __restrict__ bo, float* __restrict__ out)
{
    __shared__ float red[4][8];
    const long b   = blockIdx.x;
    const int tid  = threadIdx.x;
    const int lane = tid & 63;
    const int wave = tid >> 6;
    float acc[5] = {0.f, 0.f, 0.f, 0.f, 0.f};
    const _Float16* f = F + b * KP;

    const int c1 = (wave + 1) * 402;
    for (int c = wave * 402 + lane; c < c1; c += 64) {
        const int k = c << 2;
        v4h f4 = *(const v4h*)(f + k);
        const float f0 = (float)f4[0], f1 = (float)f4[1];
        const float f2 = (float)f4[2], f3 = (float)f4[3];
        #pragma unroll
        for (int o = 0; o < 5; ++o) {
            const float4 w4 = *(const float4*)(wo + o * GK + k);
            acc[o] += f0 * w4.x + f1 * w4.y + f2 * w4.z + f3 * w4.w;
        }
    }
    #pragma unroll
    for (int o = 0; o < 5; ++o) {
        #pragma unroll
        for (int off = 32; off > 0; off >>= 1) acc[o] += __shfl_down(acc[o], off, 64);
    }
    if (lane == 0) {
        #pragma unroll
        for (int o = 0; o < 5; ++o) red[wave][o] = acc[o];
    }
    __syncthreads();
    if (tid < 5)
        out[b * 5 + tid] = red[0][tid] + red[1][tid] + red[2][tid] + red[3][tid] + bo[tid];
}

// ---------------------------------------------------------------------------
extern "C" void kernel_launch(void* const* d_in, const int* in_sizes, int n_in,
                              void* d_out, int out_size, void* d_ws, size_t ws_size,
                              hipStream_t stream)
{
    const float* x  = (const float*)d_in[0];
    const float* w1 = (const float*)d_in[1];
    const float* b1 = (const float*)d_in[2];
    const float* w2 = (const float*)d_in[3];
    const float* b2 = (const float*)d_in[4];
    const float* wl = (const float*)d_in[5];
    const float* bl = (const float*)d_in[6];
    const float* wo = (const float*)d_in[7];
    const float* bo = (const float*)d_in[8];
    float* out = (float*)d_out;

    char* ws = (char*)d_ws;
    _Float16* Wh = (_Float16*)ws;                                   // 6432*6528*2 = 83,976,192 B
    _Float16* F0 = (_Float16*)(ws + 83976192);                      // 2048*6528*2 = 26,738,688 B
    _Float16* F1 = (_Float16*)(ws + 83976192 + 26738688);

    convert_w<<<dim3(7, GN), 256, 0, stream>>>(wl, Wh);
    conv_feat<<<GM, 256, 0, stream>>>(x, w1, b1, w2, b2, F0);
    gemm8<<<208, 512, 0, stream>>>(F0, Wh, bl, F1);
    gemm8<<<208, 512, 0, stream>>>(F1, Wh, bl, F0);
    gemm8<<<208, 512, 0, stream>>>(F0, Wh, bl, F1);
    gemm8<<<208, 512, 0, stream>>>(F1, Wh, bl, F0);
    final_out<<<GM, 256, 0, stream>>>(F0, wo, bo, out);
}